// Round 5
// baseline (432.081 us; speedup 1.0000x reference)
//
#include <hip/hip_runtime.h>
#include <hip/hip_bf16.h>
#include <cstdint>

#define B_ 16
#define N_ 1024
#define D_ 256
#define H_ 128

typedef unsigned short u16;
typedef __attribute__((ext_vector_type(8))) short bf16x8;
typedef __attribute__((ext_vector_type(4))) float f32x4;

__device__ __forceinline__ u16 f2bf(float f) {
    union { float f; uint32_t u; } v; v.f = f;
    return (u16)((v.u + 0x7FFFu + ((v.u >> 16) & 1u)) >> 16);  // RNE
}
__device__ __forceinline__ float bf2f(u16 h) {
    union { uint32_t u; float f; } v; v.u = ((uint32_t)h) << 16; return v.f;
}

typedef __attribute__((address_space(3))) void lds_void;
typedef const __attribute__((address_space(1))) void g_void;

__device__ __forceinline__ void gl_lds16(const void* g, void* l) {
    // async global->LDS, 16B/lane; LDS dest = wave-uniform base + lane*16
    __builtin_amdgcn_global_load_lds((g_void*)g, (lds_void*)l, 16, 0, 0);
}

// ---------------------------------------------------------------------------
// K1: fp32 adjacencies -> bf16 (normal + transposed copies). Run once.
// 64x64 tiles for 128B write segments. grid (N/64, N/64, B*2), block 256.
__global__ __launch_bounds__(256) void k_conv_adj(
    const float* __restrict__ dep, const float* __restrict__ lat,
    u16* __restrict__ depb, u16* __restrict__ latb,
    u16* __restrict__ depTb, u16* __restrict__ latTb)
{
    __shared__ float tile[64][65];
    const int bz = blockIdx.z;
    const int b = bz >> 1;
    const float* src = (bz & 1) ? lat : dep;
    u16* dstN = (bz & 1) ? latb : depb;
    u16* dstT = (bz & 1) ? latTb : depTb;
    const int r0 = blockIdx.y * 64, c0 = blockIdx.x * 64;
    const int t = threadIdx.x;
    const int r = t >> 2, cq = (t & 3) * 16;

    const float* sp = src + ((size_t)b * N_ + r0 + r) * N_ + c0 + cq;
    u16* np = dstN + ((size_t)b * N_ + r0 + r) * N_ + c0 + cq;
    #pragma unroll
    for (int u = 0; u < 4; ++u) {
        const float4 v = *(const float4*)(sp + u * 4);
        ushort4 nv;
        nv.x = f2bf(v.x); nv.y = f2bf(v.y); nv.z = f2bf(v.z); nv.w = f2bf(v.w);
        *(ushort4*)(np + u * 4) = nv;
        tile[r][cq + u * 4]     = v.x; tile[r][cq + u * 4 + 1] = v.y;
        tile[r][cq + u * 4 + 2] = v.z; tile[r][cq + u * 4 + 3] = v.w;
    }
    __syncthreads();

    const int oc = t >> 2;            // output row = source col c0+oc
    const int iq = (t & 3) * 16;      // source rows -> output cols
    u16* tp = dstT + ((size_t)b * N_ + c0 + oc) * N_ + r0 + iq;
    #pragma unroll
    for (int u = 0; u < 4; ++u) {
        ushort4 wv;
        wv.x = f2bf(tile[iq + u * 4][oc]);
        wv.y = f2bf(tile[iq + u * 4 + 1][oc]);
        wv.z = f2bf(tile[iq + u * 4 + 2][oc]);
        wv.w = f2bf(tile[iq + u * 4 + 3][oc]);
        *(ushort4*)(tp + u * 4) = wv;
    }
}

// ---------------------------------------------------------------------------
// K2: layer-0 refine gate + x -> bf16 transposed [B,D,N] + bf16 row [B,N,D].
// grid (N/32, B), block 256.
__global__ __launch_bounds__(256) void k_gate_xt(
    const float* __restrict__ x, const float* __restrict__ rg,
    float* __restrict__ gate, u16* __restrict__ xT, u16* __restrict__ xrow)
{
    __shared__ u16 lx[D_][36];     // [d][n], pad to 36 for 8B-aligned rows
    __shared__ float srg[D_];
    const int b = blockIdx.y, n0 = blockIdx.x * 32;
    const int t = threadIdx.x;
    srg[t] = rg[t];
    __syncthreads();

    const int r = t >> 3, cg = t & 7;  // row r (0..31), 8 threads/row
    const float* xrp = x + ((size_t)b * N_ + n0 + r) * D_;
    u16* xwp = xrow + ((size_t)b * N_ + n0 + r) * D_;
    float dot = 0.f;
    #pragma unroll
    for (int u = 0; u < 8; ++u) {
        const int c = cg * 32 + u * 4;
        const float4 v = *(const float4*)(xrp + c);
        ushort4 wv;
        wv.x = f2bf(v.x); wv.y = f2bf(v.y); wv.z = f2bf(v.z); wv.w = f2bf(v.w);
        *(ushort4*)(xwp + c) = wv;
        lx[c][r] = wv.x; lx[c + 1][r] = wv.y;
        lx[c + 2][r] = wv.z; lx[c + 3][r] = wv.w;
        dot += v.x * srg[c] + v.y * srg[c + 1] + v.z * srg[c + 2] + v.w * srg[c + 3];
    }
    dot += __shfl_down(dot, 4, 8);
    dot += __shfl_down(dot, 2, 8);
    dot += __shfl_down(dot, 1, 8);
    if (cg == 0) gate[(size_t)b * N_ + n0 + r] = 1.f / (1.f + expf(-dot));
    __syncthreads();

    #pragma unroll
    for (int i = 0; i < 8; ++i) {
        const int unit = i * 256 + t;
        const int d = unit >> 3, nch = (unit & 7) * 4;
        ushort4 wv;
        wv.x = lx[d][nch];     wv.y = lx[d][nch + 1];
        wv.z = lx[d][nch + 2]; wv.w = lx[d][nch + 3];
        *(ushort4*)(xT + ((size_t)b * D_ + d) * N_ + n0 + nch) = wv;
    }
}

// ---------------------------------------------------------------------------
// K3: dual-A MFMA GEMM: Ax = g*(A1@x) + (1-g)*(A2@x), then gcn-gate + x.
// z=0: (dep,lat,Wgi,bgi)->axin ; z=1: (depT,latT,Wgo,bgo)->axout
// grid (N/32, B, 2), block 256 (4 waves). Tile 32 rows x 256 cols, BK=64
// (two 32-k halves staged per barrier, computed sequentially => 32 MFMA/wave
// per barrier at round-3 register budget). LDS exactly 40KB => 4 blocks/CU.
__global__ __launch_bounds__(256, 4) void k_gemm_ax(
    const u16* __restrict__ depb, const u16* __restrict__ latb,
    const u16* __restrict__ depTb, const u16* __restrict__ latTb,
    const u16* __restrict__ xT,
    const float* __restrict__ gate,
    const float* __restrict__ Wgi, const float* __restrict__ Wgo,
    const float* __restrict__ bgi, const float* __restrict__ bgo,
    const u16* __restrict__ xrow,
    u16* __restrict__ axin, u16* __restrict__ axout)
{
    __shared__ __align__(16) char smem[40960];
    u16* su = (u16*)smem;
    // staging (u16 offsets): A1 @0 (2 halves x 1024), A2 @2048, B @4096 (2 x 8192)
    float* hbuf = (float*)smem;                  // epilogue alias: [32][260]
    float* sh_g = (float*)(smem + 33280);        // staging-dead tail in epilogue
    float* sh_s = (float*)(smem + 33536);

    const int b = blockIdx.y;
    const int m0 = blockIdx.x * 32;
    const int z = blockIdx.z;
    const u16* A1 = z ? depTb : depb;
    const u16* A2 = z ? latTb : latb;
    const float* Wg = z ? Wgo : Wgi;
    const float bg0 = z ? bgo[0] : bgi[0];
    u16* outp = z ? axout : axin;

    const int t = threadIdx.x;
    const int lane = t & 63;
    const int w = t >> 6;

    f32x4 acc1[2][4], acc2[2][4];
    const f32x4 fz = {0.f, 0.f, 0.f, 0.f};
    #pragma unroll
    for (int i = 0; i < 2; ++i)
        #pragma unroll
        for (int j = 0; j < 4; ++j) { acc1[i][j] = fz; acc2[i][j] = fz; }

    // 40 x 1KB staging chunks, 10 per wave
    const u16* gsrc[10];
    u16* ldst[10];
    #pragma unroll
    for (int ci = 0; ci < 10; ++ci) {
        const int c = w * 10 + ci;
        const int el = lane * 8;
        if (c < 8) {
            const int mat = c >> 2, half = (c >> 1) & 1, cc = c & 1;
            const int e = cc * 512 + el;
            const int m = e >> 5, k = e & 31;
            const u16* base = mat ? A2 : A1;
            gsrc[ci] = base + ((size_t)b * N_ + m0 + m) * N_ + half * 32 + k;
            ldst[ci] = su + mat * 2048 + half * 1024 + cc * 512;
        } else {
            const int idx = c - 8;
            const int half = idx >> 4, cc = idx & 15;
            const int e = cc * 512 + el;
            const int n = e >> 5, k = e & 31;
            gsrc[ci] = xT + ((size_t)b * D_ + n) * N_ + half * 32 + k;
            ldst[ci] = su + 4096 + half * 8192 + cc * 512;
        }
    }

    const int mrow = lane & 15;
    const int kg = (lane >> 4) * 8;

    for (int ks = 0; ks < N_ / 64; ++ks) {
        #pragma unroll
        for (int ci = 0; ci < 10; ++ci) gl_lds16(gsrc[ci], ldst[ci]);
        __syncthreads();
        #pragma unroll
        for (int h = 0; h < 2; ++h) {
            bf16x8 a1[2], a2[2], fb[4];
            #pragma unroll
            for (int mt = 0; mt < 2; ++mt) {
                a1[mt] = *(const bf16x8*)(su + h * 1024 + (mt * 16 + mrow) * 32 + kg);
                a2[mt] = *(const bf16x8*)(su + 2048 + h * 1024 + (mt * 16 + mrow) * 32 + kg);
            }
            #pragma unroll
            for (int nt = 0; nt < 4; ++nt)
                fb[nt] = *(const bf16x8*)(su + 4096 + h * 8192 + (w * 64 + nt * 16 + mrow) * 32 + kg);
            #pragma unroll
            for (int mt = 0; mt < 2; ++mt)
                #pragma unroll
                for (int nt = 0; nt < 4; ++nt) {
                    acc1[mt][nt] = __builtin_amdgcn_mfma_f32_16x16x32_bf16(a1[mt], fb[nt], acc1[mt][nt], 0, 0, 0);
                    acc2[mt][nt] = __builtin_amdgcn_mfma_f32_16x16x32_bf16(a2[mt], fb[nt], acc2[mt][nt], 0, 0, 0);
                }
        }
        __syncthreads();
        #pragma unroll
        for (int ci = 0; ci < 10; ++ci) gsrc[ci] += 64;
    }

    // epilogue (staging now dead; sh_g/sh_s live in its tail)
    if (t < 32) sh_g[t] = gate[(size_t)b * N_ + m0 + t];
    __syncthreads();

    // gate blend into hbuf (C layout: col=lane&15, row=(lane>>4)*4+reg)
    const int hi = lane >> 4;
    #pragma unroll
    for (int mt = 0; mt < 2; ++mt)
        #pragma unroll
        for (int nt = 0; nt < 4; ++nt) {
            const int col = w * 64 + nt * 16 + mrow;
            #pragma unroll
            for (int rr = 0; rr < 4; ++rr) {
                const int row = mt * 16 + hi * 4 + rr;
                const float g = sh_g[row];
                hbuf[row * 260 + col] = g * acc1[mt][nt][rr] + (1.f - g) * acc2[mt][nt][rr];
            }
        }
    __syncthreads();

    {   // per-row dot with Wg -> sigmoid
        const int rr = t >> 3;
        const int c0 = (t & 7) * 32;
        float dot = 0.f;
        #pragma unroll 8
        for (int u = 0; u < 32; ++u) dot += hbuf[rr * 260 + c0 + u] * Wg[c0 + u];
        dot += __shfl_down(dot, 4, 8);
        dot += __shfl_down(dot, 2, 8);
        dot += __shfl_down(dot, 1, 8);
        if ((t & 7) == 0) sh_s[rr] = 1.f / (1.f + expf(-dot));
    }
    __syncthreads();

    #pragma unroll
    for (int i = 0; i < 16; ++i) {
        const int row = (t >> 7) + i * 2;
        const int c = (t & 127) * 2;
        const float s = sh_s[row];
        const size_t gidx = ((size_t)b * N_ + m0 + row) * D_ + c;
        const ushort2 xv = *(const ushort2*)(xrow + gidx);
        const float v0 = hbuf[row * 260 + c] * s + bg0 + bf2f(xv.x);
        const float v1 = hbuf[row * 260 + c + 1] * s + bg0 + bf2f(xv.y);
        *(ushort2*)(outp + gidx) = make_ushort2(f2bf(v0), f2bf(v1));
    }
}

// ---------------------------------------------------------------------------
// K4: h = [axin@Wi^T + 2bi, axout@Wo^T + 2bo]; LayerNorm; exact GELU.
// Last layer: writes fp32 d_out. Other layers: writes next-layer bf16 xrow,
// bf16 xT (transposed), and next-layer refine gate (fused).
// grid (N/32, B), block 256. Waves 0,1 -> in-half; 2,3 -> out-half.
__global__ __launch_bounds__(256) void k_fc_ln(
    const u16* __restrict__ axin, const u16* __restrict__ axout,
    const u16* __restrict__ Wib, const u16* __restrict__ Wob,
    const float* __restrict__ bi, const float* __restrict__ bo,
    const float* __restrict__ lg, const float* __restrict__ lb,
    const float* __restrict__ rg_next,
    float* __restrict__ gate_out, u16* __restrict__ xT_out,
    u16* __restrict__ xrow_out,
    float* __restrict__ outf)
{
    __shared__ __align__(16) char smem[33280];
    u16* sAin = (u16*)smem;         // [32][32]
    u16* sAout = sAin + 1024;
    u16* sWi = sAout + 1024;        // [128][32]
    u16* sWo = sWi + 4096;
    float* hbuf = (float*)smem;     // epilogue alias [32][260]
    __shared__ float sh_mu[32], sh_rs[32];

    const int b = blockIdx.y, m0 = blockIdx.x * 32;
    const int t = threadIdx.x, lane = t & 63, w = t >> 6;
    const int half = w >> 1, wn = w & 1;

    f32x4 acc[2][4];
    const f32x4 fz = {0.f, 0.f, 0.f, 0.f};
    #pragma unroll
    for (int i = 0; i < 2; ++i)
        #pragma unroll
        for (int j = 0; j < 4; ++j) acc[i][j] = fz;

    const u16* gsrc[5];
    u16* ldst[5];
    #pragma unroll
    for (int ci = 0; ci < 5; ++ci) {
        const int c = w * 5 + ci;
        const int el = lane * 8;
        if (c < 4) {
            const int cc = c & 1;
            const int e = cc * 512 + el;
            const int m = e >> 5, k = e & 31;
            const u16* base = (c < 2) ? axin : axout;
            gsrc[ci] = base + ((size_t)b * N_ + m0 + m) * D_ + k;
            ldst[ci] = ((c < 2) ? sAin : sAout) + cc * 512;
        } else {
            const int cc = (c - 4) & 7;
            const int e = cc * 512 + el;
            const int n = e >> 5, k = e & 31;
            const u16* base = (c < 12) ? Wib : Wob;
            gsrc[ci] = base + (size_t)n * D_ + k;
            ldst[ci] = ((c < 12) ? sWi : sWo) + cc * 512;
        }
    }

    const u16* sA = half ? sAout : sAin;
    const u16* sW = half ? sWo : sWi;
    const int mrow = lane & 15;
    const int kg = (lane >> 4) * 8;

    for (int ks = 0; ks < D_ / 32; ++ks) {
        #pragma unroll
        for (int ci = 0; ci < 5; ++ci) gl_lds16(gsrc[ci], ldst[ci]);
        __syncthreads();
        bf16x8 a[2], fb[4];
        #pragma unroll
        for (int mt = 0; mt < 2; ++mt)
            a[mt] = *(const bf16x8*)(sA + (mt * 16 + mrow) * 32 + kg);
        #pragma unroll
        for (int nt = 0; nt < 4; ++nt)
            fb[nt] = *(const bf16x8*)(sW + (wn * 64 + nt * 16 + mrow) * 32 + kg);
        #pragma unroll
        for (int mt = 0; mt < 2; ++mt)
            #pragma unroll
            for (int nt = 0; nt < 4; ++nt)
                acc[mt][nt] = __builtin_amdgcn_mfma_f32_16x16x32_bf16(a[mt], fb[nt], acc[mt][nt], 0, 0, 0);
        __syncthreads();
        #pragma unroll
        for (int ci = 0; ci < 5; ++ci) gsrc[ci] += 32;
    }

    const int hi = lane >> 4;
    #pragma unroll
    for (int mt = 0; mt < 2; ++mt)
        #pragma unroll
        for (int nt = 0; nt < 4; ++nt) {
            const int colh = wn * 64 + nt * 16 + mrow;     // 0..127 within half
            const int col = half * 128 + colh;
            const float bias = 2.f * (half ? bo[colh] : bi[colh]);
            #pragma unroll
            for (int rr = 0; rr < 4; ++rr) {
                const int row = mt * 16 + hi * 4 + rr;
                hbuf[row * 260 + col] = acc[mt][nt][rr] + bias;
            }
        }
    __syncthreads();

    {   // LN stats per row
        const int rr = t >> 3;
        const int c0 = (t & 7) * 32;
        float s = 0.f, ss = 0.f;
        #pragma unroll 8
        for (int u = 0; u < 32; ++u) {
            const float v = hbuf[rr * 260 + c0 + u];
            s += v; ss += v * v;
        }
        s += __shfl_down(s, 4, 8);  ss += __shfl_down(ss, 4, 8);
        s += __shfl_down(s, 2, 8);  ss += __shfl_down(ss, 2, 8);
        s += __shfl_down(s, 1, 8);  ss += __shfl_down(ss, 1, 8);
        if ((t & 7) == 0) {
            const float mu = s * (1.f / 256.f);
            const float var = ss * (1.f / 256.f) - mu * mu;
            sh_mu[rr] = mu;
            sh_rs[rr] = rsqrtf(var + 1e-5f);
        }
    }
    __syncthreads();

    if (outf) {
        #pragma unroll
        for (int i = 0; i < 16; ++i) {
            const int row = (t >> 7) + i * 2;
            const int c = (t & 127) * 2;
            const float mu = sh_mu[row], rs = sh_rs[row];
            const float2 gg = *(const float2*)(lg + c);
            const float2 bb = *(const float2*)(lb + c);
            const float v0 = (hbuf[row * 260 + c] - mu) * rs * gg.x + bb.x;
            const float v1 = (hbuf[row * 260 + c + 1] - mu) * rs * gg.y + bb.y;
            const float y0 = 0.5f * v0 * (1.f + erff(v0 * 0.70710678118654752f));
            const float y1 = 0.5f * v1 * (1.f + erff(v1 * 0.70710678118654752f));
            const size_t gidx = ((size_t)b * N_ + m0 + row) * D_ + c;
            *(float2*)(outf + gidx) = make_float2(y0, y1);
        }
    } else {
        // write bf16 xrow, stash y back into hbuf for gate-dot + transpose
        #pragma unroll
        for (int i = 0; i < 16; ++i) {
            const int row = (t >> 7) + i * 2;
            const int c = (t & 127) * 2;
            const float mu = sh_mu[row], rs = sh_rs[row];
            const float2 gg = *(const float2*)(lg + c);
            const float2 bb = *(const float2*)(lb + c);
            const float v0 = (hbuf[row * 260 + c] - mu) * rs * gg.x + bb.x;
            const float v1 = (hbuf[row * 260 + c + 1] - mu) * rs * gg.y + bb.y;
            const float y0 = 0.5f * v0 * (1.f + erff(v0 * 0.70710678118654752f));
            const float y1 = 0.5f * v1 * (1.f + erff(v1 * 0.70710678118654752f));
            hbuf[row * 260 + c] = y0;
            hbuf[row * 260 + c + 1] = y1;
            const size_t gidx = ((size_t)b * N_ + m0 + row) * D_ + c;
            *(ushort2*)(xrow_out + gidx) = make_ushort2(f2bf(y0), f2bf(y1));
        }
        __syncthreads();

        {   // next-layer refine gate: sigmoid(y . rg_next)
            const int rr = t >> 3;
            const int c0 = (t & 7) * 32;
            float dot = 0.f;
            #pragma unroll 8
            for (int u = 0; u < 32; ++u) dot += hbuf[rr * 260 + c0 + u] * rg_next[c0 + u];
            dot += __shfl_down(dot, 4, 8);
            dot += __shfl_down(dot, 2, 8);
            dot += __shfl_down(dot, 1, 8);
            if ((t & 7) == 0) gate_out[(size_t)b * N_ + m0 + rr] = 1.f / (1.f + expf(-dot));
        }

        // transposed bf16 xT[b][d][n]
        #pragma unroll
        for (int i = 0; i < 8; ++i) {
            const int unit = i * 256 + t;
            const int d = unit >> 3, nch = (unit & 7) * 4;
            ushort4 wv;
            wv.x = f2bf(hbuf[nch * 260 + d]);
            wv.y = f2bf(hbuf[(nch + 1) * 260 + d]);
            wv.z = f2bf(hbuf[(nch + 2) * 260 + d]);
            wv.w = f2bf(hbuf[(nch + 3) * 260 + d]);
            *(ushort4*)(xT_out + ((size_t)b * D_ + d) * N_ + m0 + nch) = wv;
        }
    }
}

// ---------------------------------------------------------------------------
// fp32->bf16 weight convert, BOTH layers at once (2*H*D each tensor)
__global__ __launch_bounds__(256) void k_convw(
    const float* __restrict__ wi, const float* __restrict__ wo,
    u16* __restrict__ wib, u16* __restrict__ wob)
{
    const int i = blockIdx.x * 256 + threadIdx.x;  // 65536 total
    wib[i] = f2bf(wi[i]);
    wob[i] = f2bf(wo[i]);
}

// ---------------------------------------------------------------------------
extern "C" void kernel_launch(void* const* d_in, const int* in_sizes, int n_in,
                              void* d_out, int out_size, void* d_ws, size_t ws_size,
                              hipStream_t stream)
{
    (void)in_sizes; (void)n_in; (void)out_size; (void)ws_size;

    const float* x0  = (const float*)d_in[0];
    const float* lat = (const float*)d_in[1];
    const float* dep = (const float*)d_in[2];
    const float* rg  = (const float*)d_in[3];   // [L,D,1]
    const float* Wgi = (const float*)d_in[4];   // [L,D,1]
    const float* bgi = (const float*)d_in[5];   // [L,1]
    const float* Wgo = (const float*)d_in[6];
    const float* bgo = (const float*)d_in[7];
    const float* fiW = (const float*)d_in[8];   // [L,H,D]
    const float* fib = (const float*)d_in[9];   // [L,H]
    const float* foW = (const float*)d_in[10];
    const float* fob = (const float*)d_in[11];
    const float* lng = (const float*)d_in[12];  // [L,2H]
    const float* lnb = (const float*)d_in[13];

    char* ws = (char*)d_ws;
    size_t off = 0;
    auto alloc = [&](size_t bytes) {
        char* p = ws + off;
        off += (bytes + 255) & ~(size_t)255;
        return p;
    };
    u16* depb  = (u16*)alloc(2ull * B_ * N_ * N_);
    u16* latb  = (u16*)alloc(2ull * B_ * N_ * N_);
    u16* depTb = (u16*)alloc(2ull * B_ * N_ * N_);
    u16* latTb = (u16*)alloc(2ull * B_ * N_ * N_);
    u16* xT    = (u16*)alloc(2ull * B_ * D_ * N_);
    u16* xrow  = (u16*)alloc(2ull * B_ * N_ * D_);
    u16* axin  = (u16*)alloc(2ull * B_ * N_ * D_);
    u16* axout = (u16*)alloc(2ull * B_ * N_ * D_);
    float* gate = (float*)alloc(4ull * B_ * N_);
    u16* Wib = (u16*)alloc(2ull * 2 * H_ * D_);
    u16* Wob = (u16*)alloc(2ull * 2 * H_ * D_);

    k_conv_adj<<<dim3(16, 16, 32), 256, 0, stream>>>(dep, lat, depb, latb, depTb, latTb);
    k_convw<<<256, 256, 0, stream>>>(fiW, foW, Wib, Wob);
    k_gate_xt<<<dim3(32, B_), 256, 0, stream>>>(x0, rg, gate, xT, xrow);

    for (int l = 0; l < 2; ++l) {
        k_gemm_ax<<<dim3(32, B_, 2), 256, 0, stream>>>(
            depb, latb, depTb, latTb, xT, gate,
            Wgi + l * D_, Wgo + l * D_, bgi + l, bgo + l,
            xrow, axin, axout);
        const bool last = (l == 1);
        k_fc_ln<<<dim3(32, B_), 256, 0, stream>>>(
            axin, axout, Wib + (size_t)l * H_ * D_, Wob + (size_t)l * H_ * D_,
            fib + l * H_, fob + l * H_,
            lng + l * 2 * H_, lnb + l * 2 * H_,
            rg + (l + 1 < 2 ? (l + 1) * D_ : 0),
            last ? nullptr : gate,
            last ? nullptr : xT,
            last ? nullptr : xrow,
            last ? (float*)d_out : nullptr);
    }
}

// Round 6
// 392.920 us; speedup vs baseline: 1.0997x; 1.0997x over previous
//
#include <hip/hip_runtime.h>
#include <hip/hip_bf16.h>
#include <cstdint>

#define B_ 16
#define N_ 1024
#define D_ 256
#define H_ 128

typedef unsigned short u16;
typedef __attribute__((ext_vector_type(8))) short bf16x8;
typedef __attribute__((ext_vector_type(4))) float f32x4;

__device__ __forceinline__ u16 f2bf(float f) {
    union { float f; uint32_t u; } v; v.f = f;
    return (u16)((v.u + 0x7FFFu + ((v.u >> 16) & 1u)) >> 16);  // RNE
}
__device__ __forceinline__ float bf2f(u16 h) {
    union { uint32_t u; float f; } v; v.u = ((uint32_t)h) << 16; return v.f;
}

typedef __attribute__((address_space(3))) void lds_void;
typedef const __attribute__((address_space(1))) void g_void;

__device__ __forceinline__ void gl_lds16(const void* g, void* l) {
    __builtin_amdgcn_global_load_lds((g_void*)g, (lds_void*)l, 16, 0, 0);
}
// per-wave waits (gfx9 encoding: vmcnt[3:0]|expcnt<<4|lgkmcnt<<8|vmcnt[5:4]<<14)
#define WAIT_VM0()   __builtin_amdgcn_s_waitcnt(0x0F70)  // vmcnt(0), lgkm/exp free
#define WAIT_LGKM0() __builtin_amdgcn_s_waitcnt(0xC07F)  // lgkmcnt(0), vm/exp free

// ---------------------------------------------------------------------------
// K1: fp32 adjacencies -> bf16 (normal + transposed copies). Run once.
// 64x64 tiles for 128B write segments. grid (N/64, N/64, B*2), block 256.
__global__ __launch_bounds__(256) void k_conv_adj(
    const float* __restrict__ dep, const float* __restrict__ lat,
    u16* __restrict__ depb, u16* __restrict__ latb,
    u16* __restrict__ depTb, u16* __restrict__ latTb)
{
    __shared__ float tile[64][65];
    const int bz = blockIdx.z;
    const int b = bz >> 1;
    const float* src = (bz & 1) ? lat : dep;
    u16* dstN = (bz & 1) ? latb : depb;
    u16* dstT = (bz & 1) ? latTb : depTb;
    const int r0 = blockIdx.y * 64, c0 = blockIdx.x * 64;
    const int t = threadIdx.x;
    const int r = t >> 2, cq = (t & 3) * 16;

    const float* sp = src + ((size_t)b * N_ + r0 + r) * N_ + c0 + cq;
    u16* np = dstN + ((size_t)b * N_ + r0 + r) * N_ + c0 + cq;
    #pragma unroll
    for (int u = 0; u < 4; ++u) {
        const float4 v = *(const float4*)(sp + u * 4);
        ushort4 nv;
        nv.x = f2bf(v.x); nv.y = f2bf(v.y); nv.z = f2bf(v.z); nv.w = f2bf(v.w);
        *(ushort4*)(np + u * 4) = nv;
        tile[r][cq + u * 4]     = v.x; tile[r][cq + u * 4 + 1] = v.y;
        tile[r][cq + u * 4 + 2] = v.z; tile[r][cq + u * 4 + 3] = v.w;
    }
    __syncthreads();

    const int oc = t >> 2;
    const int iq = (t & 3) * 16;
    u16* tp = dstT + ((size_t)b * N_ + c0 + oc) * N_ + r0 + iq;
    #pragma unroll
    for (int u = 0; u < 4; ++u) {
        ushort4 wv;
        wv.x = f2bf(tile[iq + u * 4][oc]);
        wv.y = f2bf(tile[iq + u * 4 + 1][oc]);
        wv.z = f2bf(tile[iq + u * 4 + 2][oc]);
        wv.w = f2bf(tile[iq + u * 4 + 3][oc]);
        *(ushort4*)(tp + u * 4) = wv;
    }
}

// ---------------------------------------------------------------------------
// K2: layer-0 refine gate + x -> bf16 transposed [B,D,N] + bf16 row [B,N,D].
__global__ __launch_bounds__(256) void k_gate_xt(
    const float* __restrict__ x, const float* __restrict__ rg,
    float* __restrict__ gate, u16* __restrict__ xT, u16* __restrict__ xrow)
{
    __shared__ u16 lx[D_][36];
    __shared__ float srg[D_];
    const int b = blockIdx.y, n0 = blockIdx.x * 32;
    const int t = threadIdx.x;
    srg[t] = rg[t];
    __syncthreads();

    const int r = t >> 3, cg = t & 7;
    const float* xrp = x + ((size_t)b * N_ + n0 + r) * D_;
    u16* xwp = xrow + ((size_t)b * N_ + n0 + r) * D_;
    float dot = 0.f;
    #pragma unroll
    for (int u = 0; u < 8; ++u) {
        const int c = cg * 32 + u * 4;
        const float4 v = *(const float4*)(xrp + c);
        ushort4 wv;
        wv.x = f2bf(v.x); wv.y = f2bf(v.y); wv.z = f2bf(v.z); wv.w = f2bf(v.w);
        *(ushort4*)(xwp + c) = wv;
        lx[c][r] = wv.x; lx[c + 1][r] = wv.y;
        lx[c + 2][r] = wv.z; lx[c + 3][r] = wv.w;
        dot += v.x * srg[c] + v.y * srg[c + 1] + v.z * srg[c + 2] + v.w * srg[c + 3];
    }
    dot += __shfl_down(dot, 4, 8);
    dot += __shfl_down(dot, 2, 8);
    dot += __shfl_down(dot, 1, 8);
    if (cg == 0) gate[(size_t)b * N_ + n0 + r] = 1.f / (1.f + expf(-dot));
    __syncthreads();

    #pragma unroll
    for (int i = 0; i < 8; ++i) {
        const int unit = i * 256 + t;
        const int d = unit >> 3, nch = (unit & 7) * 4;
        ushort4 wv;
        wv.x = lx[d][nch];     wv.y = lx[d][nch + 1];
        wv.z = lx[d][nch + 2]; wv.w = lx[d][nch + 3];
        *(ushort4*)(xT + ((size_t)b * D_ + d) * N_ + n0 + nch) = wv;
    }
}

// ---------------------------------------------------------------------------
// K3: dual-A MFMA GEMM, DECOUPLED-WAVE K-loop (no barriers in loop).
// Each wave stages its own 8KB LDS region (A1 2K + A2 2K + 64-col B 4K) via
// global_load_lds and syncs with per-wave s_waitcnt vmcnt(0). Grid: 1024
// blocks 1-D, idx = m*32 + (b*2+z) so a (b,z) group's 32 blocks share an XCD.
__global__ __launch_bounds__(256, 4) void k_gemm_ax(
    const u16* __restrict__ depb, const u16* __restrict__ latb,
    const u16* __restrict__ depTb, const u16* __restrict__ latTb,
    const u16* __restrict__ xT,
    const float* __restrict__ gate,
    const float* __restrict__ Wgi, const float* __restrict__ Wgo,
    const float* __restrict__ bgi, const float* __restrict__ bgo,
    const u16* __restrict__ xrow,
    u16* __restrict__ axin, u16* __restrict__ axout)
{
    __shared__ __align__(16) char smem[33280];  // staging 32KB / epilogue 32x260 f32
    u16* su = (u16*)smem;
    float* hbuf = (float*)smem;
    __shared__ float sh_g[32];
    __shared__ float sh_s[32];

    const int idx = blockIdx.x;
    const int g = idx & 31;
    const int m0 = (idx >> 5) * 32;
    const int b = g >> 1;
    const int z = g & 1;
    const u16* A1 = z ? depTb : depb;
    const u16* A2 = z ? latTb : latb;
    const float* Wg = z ? Wgo : Wgi;
    const float bg0 = z ? bgo[0] : bgi[0];
    u16* outp = z ? axout : axin;

    const int t = threadIdx.x;
    const int lane = t & 63;
    const int w = t >> 6;
    const int wbase = w * 4096;  // u16 elements: 8KB per wave

    if (t < 32) sh_g[t] = gate[(size_t)b * N_ + m0 + t];

    f32x4 acc1[2][4], acc2[2][4];
    const f32x4 fz = {0.f, 0.f, 0.f, 0.f};
    #pragma unroll
    for (int i = 0; i < 2; ++i)
        #pragma unroll
        for (int j = 0; j < 4; ++j) { acc1[i][j] = fz; acc2[i][j] = fz; }

    // 8 x 1KB chunks per wave per step: A1 x2, A2 x2, own B quarter x4
    const u16* gsrc[8];
    u16* ldst[8];
    {
        const int mr = lane >> 2;            // 16 rows per chunk
        const int kk = (lane & 3) * 8;
        #pragma unroll
        for (int cc = 0; cc < 2; ++cc) {
            gsrc[cc]     = A1 + ((size_t)b * N_ + m0 + cc * 16 + mr) * N_ + kk;
            ldst[cc]     = su + wbase + cc * 512;
            gsrc[2 + cc] = A2 + ((size_t)b * N_ + m0 + cc * 16 + mr) * N_ + kk;
            ldst[2 + cc] = su + wbase + 1024 + cc * 512;
        }
        #pragma unroll
        for (int cc = 0; cc < 4; ++cc) {
            gsrc[4 + cc] = xT + ((size_t)b * D_ + w * 64 + cc * 16 + mr) * N_ + kk;
            ldst[4 + cc] = su + wbase + 2048 + cc * 512;
        }
    }

    const int mrow = lane & 15;
    const int kg = (lane >> 4) * 8;

    // prologue: issue step-0 loads
    #pragma unroll
    for (int ci = 0; ci < 8; ++ci) gl_lds16(gsrc[ci], ldst[ci]);

    for (int ks = 0; ks < N_ / 32; ++ks) {
        WAIT_VM0();                      // this wave's staged tile is resident
        bf16x8 a1[2], a2[2], fb[4];
        #pragma unroll
        for (int mt = 0; mt < 2; ++mt) {
            a1[mt] = *(const bf16x8*)(su + wbase + (mt * 16 + mrow) * 32 + kg);
            a2[mt] = *(const bf16x8*)(su + wbase + 1024 + (mt * 16 + mrow) * 32 + kg);
        }
        #pragma unroll
        for (int nt = 0; nt < 4; ++nt)
            fb[nt] = *(const bf16x8*)(su + wbase + 2048 + (nt * 16 + mrow) * 32 + kg);
        WAIT_LGKM0();                    // fragments in VGPRs; LDS reusable
        if (ks < N_ / 32 - 1) {
            #pragma unroll
            for (int ci = 0; ci < 8; ++ci) {
                gsrc[ci] += 32;
                gl_lds16(gsrc[ci], ldst[ci]);
            }
        }
        #pragma unroll
        for (int mt = 0; mt < 2; ++mt)
            #pragma unroll
            for (int nt = 0; nt < 4; ++nt) {
                acc1[mt][nt] = __builtin_amdgcn_mfma_f32_16x16x32_bf16(a1[mt], fb[nt], acc1[mt][nt], 0, 0, 0);
                acc2[mt][nt] = __builtin_amdgcn_mfma_f32_16x16x32_bf16(a2[mt], fb[nt], acc2[mt][nt], 0, 0, 0);
            }
    }
    __syncthreads();   // realign waves; staging dead, hbuf epilogue begins

    // gate blend into hbuf (C layout: col=lane&15, row=(lane>>4)*4+reg)
    const int hi = lane >> 4;
    #pragma unroll
    for (int mt = 0; mt < 2; ++mt)
        #pragma unroll
        for (int nt = 0; nt < 4; ++nt) {
            const int col = w * 64 + nt * 16 + mrow;
            #pragma unroll
            for (int rr = 0; rr < 4; ++rr) {
                const int row = mt * 16 + hi * 4 + rr;
                const float gg = sh_g[row];
                hbuf[row * 260 + col] = gg * acc1[mt][nt][rr] + (1.f - gg) * acc2[mt][nt][rr];
            }
        }
    __syncthreads();

    {   // per-row dot with Wg -> sigmoid
        const int rr = t >> 3;
        const int c0 = (t & 7) * 32;
        float dot = 0.f;
        #pragma unroll 8
        for (int u = 0; u < 32; ++u) dot += hbuf[rr * 260 + c0 + u] * Wg[c0 + u];
        dot += __shfl_down(dot, 4, 8);
        dot += __shfl_down(dot, 2, 8);
        dot += __shfl_down(dot, 1, 8);
        if ((t & 7) == 0) sh_s[rr] = 1.f / (1.f + expf(-dot));
    }
    __syncthreads();

    #pragma unroll
    for (int i = 0; i < 16; ++i) {
        const int row = (t >> 7) + i * 2;
        const int c = (t & 127) * 2;
        const float s = sh_s[row];
        const size_t gidx = ((size_t)b * N_ + m0 + row) * D_ + c;
        const ushort2 xv = *(const ushort2*)(xrow + gidx);
        const float v0 = hbuf[row * 260 + c] * s + bg0 + bf2f(xv.x);
        const float v1 = hbuf[row * 260 + c + 1] * s + bg0 + bf2f(xv.y);
        *(ushort2*)(outp + gidx) = make_ushort2(f2bf(v0), f2bf(v1));
    }
}

// ---------------------------------------------------------------------------
// K4: h = [axin@Wi^T + 2bi, axout@Wo^T + 2bo]; LayerNorm; exact GELU.
// Decoupled-wave K-loop (6KB/wave: A-half 2K + 64-row W slice 4K).
// grid (N/32, B), block 256. Wave (half=w>>1, wn=w&1).
__global__ __launch_bounds__(256, 4) void k_fc_ln(
    const u16* __restrict__ axin, const u16* __restrict__ axout,
    const u16* __restrict__ Wib, const u16* __restrict__ Wob,
    const float* __restrict__ bi, const float* __restrict__ bo,
    const float* __restrict__ lg, const float* __restrict__ lb,
    const float* __restrict__ rg_next,
    float* __restrict__ gate_out, u16* __restrict__ xT_out,
    u16* __restrict__ xrow_out,
    float* __restrict__ outf)
{
    __shared__ __align__(16) char smem[33280];
    u16* su = (u16*)smem;
    float* hbuf = (float*)smem;
    __shared__ float sh_mu[32], sh_rs[32];

    const int b = blockIdx.y, m0 = blockIdx.x * 32;
    const int t = threadIdx.x, lane = t & 63, w = t >> 6;
    const int half = w >> 1, wn = w & 1;
    const int wbase = w * 3072;  // u16 elements: 6KB per wave

    f32x4 acc[2][4];
    const f32x4 fz = {0.f, 0.f, 0.f, 0.f};
    #pragma unroll
    for (int i = 0; i < 2; ++i)
        #pragma unroll
        for (int j = 0; j < 4; ++j) acc[i][j] = fz;

    const u16* gsrc[6];
    u16* ldst[6];
    {
        const int mr = lane >> 2;
        const int kk = (lane & 3) * 8;
        const u16* aB = half ? axout : axin;
        const u16* wB = half ? Wob : Wib;
        #pragma unroll
        for (int cc = 0; cc < 2; ++cc) {
            gsrc[cc] = aB + ((size_t)b * N_ + m0 + cc * 16 + mr) * D_ + kk;
            ldst[cc] = su + wbase + cc * 512;
        }
        #pragma unroll
        for (int cc = 0; cc < 4; ++cc) {
            gsrc[2 + cc] = wB + (size_t)(wn * 64 + cc * 16 + mr) * D_ + kk;
            ldst[2 + cc] = su + wbase + 1024 + cc * 512;
        }
    }

    const int mrow = lane & 15;
    const int kg = (lane >> 4) * 8;

    #pragma unroll
    for (int ci = 0; ci < 6; ++ci) gl_lds16(gsrc[ci], ldst[ci]);

    for (int ks = 0; ks < D_ / 32; ++ks) {
        WAIT_VM0();
        bf16x8 a[2], fb[4];
        #pragma unroll
        for (int mt = 0; mt < 2; ++mt)
            a[mt] = *(const bf16x8*)(su + wbase + (mt * 16 + mrow) * 32 + kg);
        #pragma unroll
        for (int nt = 0; nt < 4; ++nt)
            fb[nt] = *(const bf16x8*)(su + wbase + 1024 + (nt * 16 + mrow) * 32 + kg);
        WAIT_LGKM0();
        if (ks < D_ / 32 - 1) {
            #pragma unroll
            for (int ci = 0; ci < 6; ++ci) {
                gsrc[ci] += 32;
                gl_lds16(gsrc[ci], ldst[ci]);
            }
        }
        #pragma unroll
        for (int mt = 0; mt < 2; ++mt)
            #pragma unroll
            for (int nt = 0; nt < 4; ++nt)
                acc[mt][nt] = __builtin_amdgcn_mfma_f32_16x16x32_bf16(a[mt], fb[nt], acc[mt][nt], 0, 0, 0);
    }
    __syncthreads();

    const int hi = lane >> 4;
    #pragma unroll
    for (int mt = 0; mt < 2; ++mt)
        #pragma unroll
        for (int nt = 0; nt < 4; ++nt) {
            const int colh = wn * 64 + nt * 16 + mrow;
            const int col = half * 128 + colh;
            const float bias = 2.f * (half ? bo[colh] : bi[colh]);
            #pragma unroll
            for (int rr = 0; rr < 4; ++rr) {
                const int row = mt * 16 + hi * 4 + rr;
                hbuf[row * 260 + col] = acc[mt][nt][rr] + bias;
            }
        }
    __syncthreads();

    {   // LN stats per row
        const int rr = t >> 3;
        const int c0 = (t & 7) * 32;
        float s = 0.f, ss = 0.f;
        #pragma unroll 8
        for (int u = 0; u < 32; ++u) {
            const float v = hbuf[rr * 260 + c0 + u];
            s += v; ss += v * v;
        }
        s += __shfl_down(s, 4, 8);  ss += __shfl_down(ss, 4, 8);
        s += __shfl_down(s, 2, 8);  ss += __shfl_down(ss, 2, 8);
        s += __shfl_down(s, 1, 8);  ss += __shfl_down(ss, 1, 8);
        if ((t & 7) == 0) {
            const float mu = s * (1.f / 256.f);
            const float var = ss * (1.f / 256.f) - mu * mu;
            sh_mu[rr] = mu;
            sh_rs[rr] = rsqrtf(var + 1e-5f);
        }
    }
    __syncthreads();

    if (outf) {
        #pragma unroll
        for (int i = 0; i < 16; ++i) {
            const int row = (t >> 7) + i * 2;
            const int c = (t & 127) * 2;
            const float mu = sh_mu[row], rs = sh_rs[row];
            const float2 gg = *(const float2*)(lg + c);
            const float2 bb = *(const float2*)(lb + c);
            const float v0 = (hbuf[row * 260 + c] - mu) * rs * gg.x + bb.x;
            const float v1 = (hbuf[row * 260 + c + 1] - mu) * rs * gg.y + bb.y;
            const float y0 = 0.5f * v0 * (1.f + erff(v0 * 0.70710678118654752f));
            const float y1 = 0.5f * v1 * (1.f + erff(v1 * 0.70710678118654752f));
            const size_t gidx = ((size_t)b * N_ + m0 + row) * D_ + c;
            *(float2*)(outf + gidx) = make_float2(y0, y1);
        }
    } else {
        #pragma unroll
        for (int i = 0; i < 16; ++i) {
            const int row = (t >> 7) + i * 2;
            const int c = (t & 127) * 2;
            const float mu = sh_mu[row], rs = sh_rs[row];
            const float2 gg = *(const float2*)(lg + c);
            const float2 bb = *(const float2*)(lb + c);
            const float v0 = (hbuf[row * 260 + c] - mu) * rs * gg.x + bb.x;
            const float v1 = (hbuf[row * 260 + c + 1] - mu) * rs * gg.y + bb.y;
            const float y0 = 0.5f * v0 * (1.f + erff(v0 * 0.70710678118654752f));
            const float y1 = 0.5f * v1 * (1.f + erff(v1 * 0.70710678118654752f));
            hbuf[row * 260 + c] = y0;
            hbuf[row * 260 + c + 1] = y1;
            const size_t gidx = ((size_t)b * N_ + m0 + row) * D_ + c;
            *(ushort2*)(xrow_out + gidx) = make_ushort2(f2bf(y0), f2bf(y1));
        }
        __syncthreads();

        {   // next-layer refine gate
            const int rr = t >> 3;
            const int c0 = (t & 7) * 32;
            float dot = 0.f;
            #pragma unroll 8
            for (int u = 0; u < 32; ++u) dot += hbuf[rr * 260 + c0 + u] * rg_next[c0 + u];
            dot += __shfl_down(dot, 4, 8);
            dot += __shfl_down(dot, 2, 8);
            dot += __shfl_down(dot, 1, 8);
            if ((t & 7) == 0) gate_out[(size_t)b * N_ + m0 + rr] = 1.f / (1.f + expf(-dot));
        }

        #pragma unroll
        for (int i = 0; i < 8; ++i) {
            const int unit = i * 256 + t;
            const int d = unit >> 3, nch = (unit & 7) * 4;
            ushort4 wv;
            wv.x = f2bf(hbuf[nch * 260 + d]);
            wv.y = f2bf(hbuf[(nch + 1) * 260 + d]);
            wv.z = f2bf(hbuf[(nch + 2) * 260 + d]);
            wv.w = f2bf(hbuf[(nch + 3) * 260 + d]);
            *(ushort4*)(xT_out + ((size_t)b * D_ + d) * N_ + m0 + nch) = wv;
        }
    }
}

// ---------------------------------------------------------------------------
__global__ __launch_bounds__(256) void k_convw(
    const float* __restrict__ wi, const float* __restrict__ wo,
    u16* __restrict__ wib, u16* __restrict__ wob)
{
    const int i = blockIdx.x * 256 + threadIdx.x;  // 65536 total
    wib[i] = f2bf(wi[i]);
    wob[i] = f2bf(wo[i]);
}

// ---------------------------------------------------------------------------
extern "C" void kernel_launch(void* const* d_in, const int* in_sizes, int n_in,
                              void* d_out, int out_size, void* d_ws, size_t ws_size,
                              hipStream_t stream)
{
    (void)in_sizes; (void)n_in; (void)out_size; (void)ws_size;

    const float* x0  = (const float*)d_in[0];
    const float* lat = (const float*)d_in[1];
    const float* dep = (const float*)d_in[2];
    const float* rg  = (const float*)d_in[3];
    const float* Wgi = (const float*)d_in[4];
    const float* bgi = (const float*)d_in[5];
    const float* Wgo = (const float*)d_in[6];
    const float* bgo = (const float*)d_in[7];
    const float* fiW = (const float*)d_in[8];
    const float* fib = (const float*)d_in[9];
    const float* foW = (const float*)d_in[10];
    const float* fob = (const float*)d_in[11];
    const float* lng = (const float*)d_in[12];
    const float* lnb = (const float*)d_in[13];

    char* ws = (char*)d_ws;
    size_t off = 0;
    auto alloc = [&](size_t bytes) {
        char* p = ws + off;
        off += (bytes + 255) & ~(size_t)255;
        return p;
    };
    u16* depb  = (u16*)alloc(2ull * B_ * N_ * N_);
    u16* latb  = (u16*)alloc(2ull * B_ * N_ * N_);
    u16* depTb = (u16*)alloc(2ull * B_ * N_ * N_);
    u16* latTb = (u16*)alloc(2ull * B_ * N_ * N_);
    u16* xT    = (u16*)alloc(2ull * B_ * D_ * N_);
    u16* xrow  = (u16*)alloc(2ull * B_ * N_ * D_);
    u16* axin  = (u16*)alloc(2ull * B_ * N_ * D_);
    u16* axout = (u16*)alloc(2ull * B_ * N_ * D_);
    float* gate = (float*)alloc(4ull * B_ * N_);
    u16* Wib = (u16*)alloc(2ull * 2 * H_ * D_);
    u16* Wob = (u16*)alloc(2ull * 2 * H_ * D_);

    k_conv_adj<<<dim3(16, 16, 32), 256, 0, stream>>>(dep, lat, depb, latb, depTb, latTb);
    k_convw<<<256, 256, 0, stream>>>(fiW, foW, Wib, Wob);
    k_gate_xt<<<dim3(32, B_), 256, 0, stream>>>(x0, rg, gate, xT, xrow);

    for (int l = 0; l < 2; ++l) {
        k_gemm_ax<<<1024, 256, 0, stream>>>(
            depb, latb, depTb, latTb, xT, gate,
            Wgi + l * D_, Wgo + l * D_, bgi + l, bgo + l,
            xrow, axin, axout);
        const bool last = (l == 1);
        k_fc_ln<<<dim3(32, B_), 256, 0, stream>>>(
            axin, axout, Wib + (size_t)l * H_ * D_, Wob + (size_t)l * H_ * D_,
            fib + l * H_, fob + l * H_,
            lng + l * 2 * H_, lnb + l * 2 * H_,
            rg + (l + 1 < 2 ? (l + 1) * D_ : 0),
            last ? nullptr : gate,
            last ? nullptr : xT,
            last ? nullptr : xrow,
            last ? (float*)d_out : nullptr);
    }
}